// Round 1
// baseline (413.892 us; speedup 1.0000x reference)
//
#include <hip/hip_runtime.h>

#define BB 4
#define HH 384
#define WW 384
#define HWSZ (HH * WW)
#define KK 64
#define INFV 0x7F7F7F7F

__device__ __forceinline__ int ufind(const int* par, int i) {
    int p = par[i];
    while (p != i) { i = p; p = par[i]; }
    return i;
}

__device__ __forceinline__ void uunion(int* par, int a, int b) {
    while (true) {
        a = ufind(par, a);
        b = ufind(par, b);
        if (a == b) return;
        if (a > b) { int t = a; a = b; b = t; }
        int old = atomicCAS(&par[b], b, a);
        if (old == b) return;
        b = old;
    }
}

// 1. mask + parent init
__global__ void init_k(const float* __restrict__ x, int* __restrict__ parent) {
    int g = blockIdx.x * blockDim.x + threadIdx.x;
    if (g >= BB * HWSZ) return;
    float t = x[2 * g];
    float l = x[2 * g + 1];
    bool m = (t > 0.4f) || (l > 0.4f);
    int p = g % HWSZ;
    parent[g] = m ? p : -1;
}

// 2. union right/down neighbors
__global__ void merge_k(int* __restrict__ parent) {
    int g = blockIdx.x * blockDim.x + threadIdx.x;
    if (g >= BB * HWSZ) return;
    int b = g / HWSZ, p = g - b * HWSZ;
    int* par = parent + b * HWSZ;
    if (par[p] < 0) return;
    int h = p / WW, w = p - h * WW;
    if (w + 1 < WW && par[p + 1] >= 0) uunion(par, p, p + 1);
    if (h + 1 < HH && par[p + WW] >= 0) uunion(par, p, p + WW);
}

// 3. path-compress
__global__ void flat_k(int* __restrict__ parent) {
    int g = blockIdx.x * blockDim.x + threadIdx.x;
    if (g >= BB * HWSZ) return;
    int b = g / HWSZ, p = g - b * HWSZ;
    int* par = parent + b * HWSZ;
    if (par[p] >= 0) par[p] = ufind(par, p);
}

// 4. one block per batch: ordered scan, first KK roots (ascending index) get slots
__global__ void collect_k(const int* __restrict__ parent, int* __restrict__ slot) {
    int b = blockIdx.x;
    const int* par = parent + b * HWSZ;
    int* sl = slot + b * HWSZ;
    __shared__ int waveTot[4];
    __shared__ int base;
    if (threadIdx.x == 0) base = 0;
    __syncthreads();
    int lane = threadIdx.x & 63;
    int wv = threadIdx.x >> 6;
    for (int start = 0; start < HWSZ; start += 256) {
        int p = start + threadIdx.x;          // HWSZ % 256 == 0
        int v = par[p];
        bool isroot = (v == p);
        unsigned long long m = __ballot(isroot);
        int pre = __popcll(m & ((1ull << lane) - 1ull));
        if (lane == 0) waveTot[wv] = __popcll(m);
        __syncthreads();
        int off = 0;
        for (int i = 0; i < wv; ++i) off += waveTot[i];
        int total = waveTot[0] + waveTot[1] + waveTot[2] + waveTot[3];
        if (isroot) {
            int pos = base + off + pre;
            if (pos < KK) sl[p] = pos;
        }
        __syncthreads();
        if (threadIdx.x == 0) base += total;
        __syncthreads();
        if (base >= KK) break;                // uniform after sync
    }
}

// 5. per-pixel atomicMin into per-(b,k) column/row dilated-min arrays
__global__ void accum_k(const int* __restrict__ parent, const int* __restrict__ slot,
                        int* __restrict__ dcol, int* __restrict__ drow) {
    int g = blockIdx.x * blockDim.x + threadIdx.x;
    if (g >= BB * HWSZ) return;
    int b = g / HWSZ, p = g - b * HWSZ;
    int r = parent[g];
    if (r < 0) return;
    int k = slot[b * HWSZ + r];
    if (k < 0) return;
    int h = p / WW, w = p - h * WW;
    atomicMin(&dcol[(b * KK + k) * WW + w], (h >= 2) ? (h - 2) : h);
    atomicMin(&drow[(b * KK + k) * HH + h], (w >= 2) ? (w - 2) : w);
}

// 6. one block per (b,k): reproduce argmax!=0 semantics, reduce, emit bbox
__global__ __launch_bounds__(384) void bbox_k(const int* __restrict__ dcol,
                                              const int* __restrict__ drow,
                                              int* __restrict__ out) {
    int bk = blockIdx.x;
    int t = threadIdx.x;                       // 0..383, == WW == HH
    const int* dc = dcol + bk * WW;
    const int* dr = drow + bk * HH;

    int hm = dc[t];
    if (t >= 2) hm = min(hm, dc[t - 2]);
    if (t + 2 < WW) hm = min(hm, dc[t + 2]);
    bool mc = (hm < INFV) && (hm >= 1);
    int cmin = mc ? t : 0x7FFFFFFF;
    int cmax = mc ? t : -1;

    int wm = dr[t];
    if (t >= 2) wm = min(wm, dr[t - 2]);
    if (t + 2 < HH) wm = min(wm, dr[t + 2]);
    bool mr = (wm < INFV) && (wm >= 1);
    int rmin = mr ? t : 0x7FFFFFFF;
    int rmax = mr ? t : -1;

    for (int o = 1; o < 64; o <<= 1) {
        cmin = min(cmin, __shfl_xor(cmin, o));
        cmax = max(cmax, __shfl_xor(cmax, o));
        rmin = min(rmin, __shfl_xor(rmin, o));
        rmax = max(rmax, __shfl_xor(rmax, o));
    }
    __shared__ int s[4][6];
    int wv = t >> 6;
    if ((t & 63) == 0) { s[0][wv] = cmin; s[1][wv] = cmax; s[2][wv] = rmin; s[3][wv] = rmax; }
    __syncthreads();
    if (t == 0) {
        int CMin = s[0][0], CMax = s[1][0], RMin = s[2][0], RMax = s[3][0];
        for (int i = 1; i < 6; ++i) {
            CMin = min(CMin, s[0][i]); CMax = max(CMax, s[1][i]);
            RMin = min(RMin, s[2][i]); RMax = max(RMax, s[3][i]);
        }
        int x2, y2, wext, hext;
        if (RMax >= 0) { x2 = RMin; wext = RMax - RMin; } else { x2 = 0; wext = 1; }
        if (CMax >= 0) { y2 = CMin; hext = CMax - CMin; } else { y2 = 0; hext = 1; }
        out[bk * 4 + 0] = x2;
        out[bk * 4 + 1] = y2;
        out[bk * 4 + 2] = wext;
        out[bk * 4 + 3] = hext;
    }
}

extern "C" void kernel_launch(void* const* d_in, const int* in_sizes, int n_in,
                              void* d_out, int out_size, void* d_ws, size_t ws_size,
                              hipStream_t stream) {
    const float* x = (const float*)d_in[0];
    int* out = (int*)d_out;

    int* parent = (int*)d_ws;                    // BB*HWSZ
    int* slot   = parent + BB * HWSZ;            // BB*HWSZ
    int* dcol   = slot + BB * HWSZ;              // BB*KK*WW
    int* drow   = dcol + BB * KK * WW;           // BB*KK*HH

    hipMemsetAsync(slot, 0xFF, (size_t)BB * HWSZ * sizeof(int), stream);
    hipMemsetAsync(dcol, 0x7F, (size_t)BB * KK * WW * sizeof(int), stream);
    hipMemsetAsync(drow, 0x7F, (size_t)BB * KK * HH * sizeof(int), stream);

    int total = BB * HWSZ;
    int blk = 256;
    int grd = (total + blk - 1) / blk;

    init_k<<<grd, blk, 0, stream>>>(x, parent);
    merge_k<<<grd, blk, 0, stream>>>(parent);
    flat_k<<<grd, blk, 0, stream>>>(parent);
    collect_k<<<BB, 256, 0, stream>>>(parent, slot);
    accum_k<<<grd, blk, 0, stream>>>(parent, slot, dcol, drow);
    bbox_k<<<BB * KK, 384, 0, stream>>>(dcol, drow, out);
}

// Round 3
// 199.891 us; speedup vs baseline: 2.0706x; 2.0706x over previous
//
#include <hip/hip_runtime.h>

#define BB 4
#define HH 384
#define WW 384
#define HWSZ (HH * WW)
#define KK 64
#define CAP 8192
#define INFV 0x7F7F7F7F

// find with path halving (benign races: values only decrease toward root)
__device__ __forceinline__ int ufind(int* par, int i) {
    while (true) {
        int p = par[i];
        if (p == i) return i;
        int gp = par[p];
        if (gp == p) return p;
        par[i] = gp;
        i = gp;
    }
}

__device__ __forceinline__ void uunion(int* par, int a, int b) {
    while (true) {
        a = ufind(par, a);
        b = ufind(par, b);
        if (a == b) return;
        if (a > b) { int t = a; a = b; b = t; }
        int old = atomicCAS(&par[b], b, a);
        if (old == b) return;
        b = old;
    }
}

// 1. mask + parent init (also zero the per-batch root counters)
__global__ void init_k(const float* __restrict__ x, int* __restrict__ parent,
                       int* __restrict__ count) {
    int g = blockIdx.x * blockDim.x + threadIdx.x;
    if (g >= BB * HWSZ) return;
    if (g < BB) count[g] = 0;
    float t = x[2 * g];
    float l = x[2 * g + 1];
    bool m = (t > 0.4f) || (l > 0.4f);
    int p = g % HWSZ;
    parent[g] = m ? p : -1;
}

// 2. union right/down neighbors
__global__ void merge_k(int* __restrict__ parent) {
    int g = blockIdx.x * blockDim.x + threadIdx.x;
    if (g >= BB * HWSZ) return;
    int b = g / HWSZ, p = g - b * HWSZ;
    int* par = parent + b * HWSZ;
    if (par[p] < 0) return;
    int h = p / WW, w = p - h * WW;
    if (w + 1 < WW && par[p + 1] >= 0) uunion(par, p, p + 1);
    if (h + 1 < HH && par[p + WW] >= 0) uunion(par, p, p + WW);
}

// 3. gather root indices (unordered) into per-batch lists
__global__ void gather_k(const int* __restrict__ parent, int* __restrict__ count,
                         int* __restrict__ list) {
    int g = blockIdx.x * blockDim.x + threadIdx.x;
    if (g >= BB * HWSZ) return;
    int b = g / HWSZ, p = g - b * HWSZ;
    if (parent[g] == p) {
        int pos = atomicAdd(&count[b], 1);
        if (pos < CAP) list[b * CAP + pos] = p;
    }
}

// 4. one block per batch: rank roots by counting smaller indices; first KK win
__global__ __launch_bounds__(256) void select_k(const int* __restrict__ list,
                                                const int* __restrict__ count,
                                                int* __restrict__ ids) {
    int b = blockIdx.x;
    __shared__ int sl[CAP];
    int n = count[b];
    if (n > CAP) n = CAP;
    if (threadIdx.x < KK) ids[b * KK + threadIdx.x] = 0x7FFFFFFF;
    for (int i = threadIdx.x; i < n; i += 256) sl[i] = list[b * CAP + i];
    __syncthreads();
    for (int i = threadIdx.x; i < n; i += 256) {
        int v = sl[i];
        int r = 0;
        for (int j = 0; j < n; ++j) r += (sl[j] < v);
        if (r < KK) ids[b * KK + r] = v;
    }
}

// 5. per-pixel: find root, binary-search slot, atomicMin into dilated col/row mins
__global__ __launch_bounds__(256) void accum_k(int* __restrict__ parent,
                                               const int* __restrict__ ids,
                                               int* __restrict__ dcol,
                                               int* __restrict__ drow) {
    __shared__ int sids[KK];
    int g = blockIdx.x * 256 + threadIdx.x;
    int b = g / HWSZ, p = g - b * HWSZ;       // block spans one batch (HWSZ%256==0)
    if (threadIdx.x < KK) sids[threadIdx.x] = ids[b * KK + threadIdx.x];
    __syncthreads();
    if (parent[g] < 0) return;
    int r = ufind(parent + b * HWSZ, p);
    int lo = 0, hi = KK - 1, k = -1;
    while (lo <= hi) {
        int mid = (lo + hi) >> 1;
        int v = sids[mid];
        if (v == r) { k = mid; break; }
        if (v < r) lo = mid + 1; else hi = mid - 1;
    }
    if (k < 0) return;
    int h = p / WW, w = p - h * WW;
    atomicMin(&dcol[(b * KK + k) * WW + w], (h >= 2) ? (h - 2) : h);
    atomicMin(&drow[(b * KK + k) * HH + h], (w >= 2) ? (w - 2) : w);
}

// 6. one block per (b,k): reproduce argmax!=0 semantics, reduce, emit bbox
__global__ __launch_bounds__(384) void bbox_k(const int* __restrict__ dcol,
                                              const int* __restrict__ drow,
                                              int* __restrict__ out) {
    int bk = blockIdx.x;
    int t = threadIdx.x;                       // 0..383, == WW == HH
    const int* dc = dcol + bk * WW;
    const int* dr = drow + bk * HH;

    int hm = dc[t];
    if (t >= 2) hm = min(hm, dc[t - 2]);
    if (t + 2 < WW) hm = min(hm, dc[t + 2]);
    bool mc = (hm < INFV) && (hm >= 1);
    int cmin = mc ? t : 0x7FFFFFFF;
    int cmax = mc ? t : -1;

    int wm = dr[t];
    if (t >= 2) wm = min(wm, dr[t - 2]);
    if (t + 2 < HH) wm = min(wm, dr[t + 2]);
    bool mr = (wm < INFV) && (wm >= 1);
    int rmin = mr ? t : 0x7FFFFFFF;
    int rmax = mr ? t : -1;

    for (int o = 1; o < 64; o <<= 1) {
        cmin = min(cmin, __shfl_xor(cmin, o));
        cmax = max(cmax, __shfl_xor(cmax, o));
        rmin = min(rmin, __shfl_xor(rmin, o));
        rmax = max(rmax, __shfl_xor(rmax, o));
    }
    __shared__ int s[4][6];
    int wv = t >> 6;
    if ((t & 63) == 0) { s[0][wv] = cmin; s[1][wv] = cmax; s[2][wv] = rmin; s[3][wv] = rmax; }
    __syncthreads();
    if (t == 0) {
        int CMin = s[0][0], CMax = s[1][0], RMin = s[2][0], RMax = s[3][0];
        for (int i = 1; i < 6; ++i) {
            CMin = min(CMin, s[0][i]); CMax = max(CMax, s[1][i]);
            RMin = min(RMin, s[2][i]); RMax = max(RMax, s[3][i]);
        }
        int x2, y2, wext, hext;
        if (RMax >= 0) { x2 = RMin; wext = RMax - RMin; } else { x2 = 0; wext = 1; }
        if (CMax >= 0) { y2 = CMin; hext = CMax - CMin; } else { y2 = 0; hext = 1; }
        out[bk * 4 + 0] = x2;
        out[bk * 4 + 1] = y2;
        out[bk * 4 + 2] = wext;
        out[bk * 4 + 3] = hext;
    }
}

extern "C" void kernel_launch(void* const* d_in, const int* in_sizes, int n_in,
                              void* d_out, int out_size, void* d_ws, size_t ws_size,
                              hipStream_t stream) {
    const float* x = (const float*)d_in[0];
    int* out = (int*)d_out;

    int* parent = (int*)d_ws;                    // BB*HWSZ
    int* count  = parent + BB * HWSZ;            // BB
    int* ids    = count + BB;                    // BB*KK
    int* list   = ids + BB * KK;                 // BB*CAP
    int* dcol   = list + BB * CAP;               // BB*KK*WW
    int* drow   = dcol + BB * KK * WW;           // BB*KK*HH (contiguous with dcol)

    // single fused memset for dcol+drow (contiguous, both want 0x7F pattern)
    hipMemsetAsync(dcol, 0x7F, (size_t)BB * KK * (WW + HH) * sizeof(int), stream);

    int total = BB * HWSZ;
    int blk = 256;
    int grd = (total + blk - 1) / blk;

    init_k<<<grd, blk, 0, stream>>>(x, parent, count);
    merge_k<<<grd, blk, 0, stream>>>(parent);
    gather_k<<<grd, blk, 0, stream>>>(parent, count, list);
    select_k<<<BB, 256, 0, stream>>>(list, count, ids);
    accum_k<<<grd, blk, 0, stream>>>(parent, ids, dcol, drow);
    bbox_k<<<BB * KK, 384, 0, stream>>>(dcol, drow, out);
}

// Round 4
// 182.776 us; speedup vs baseline: 2.2645x; 1.0936x over previous
//
#include <hip/hip_runtime.h>

#define BB 4
#define HH 384
#define WW 384
#define HWSZ (HH * WW)
#define KK 64
#define CAP 8192
#define TS 64
#define TPS (WW / TS)            // 6 tiles per side
#define NTILE (TPS * TPS)        // 36 per batch
#define NB 576                   // histogram buckets: 147456 >> 8
#define INFV 0x7F7F7F7F

// ---- union-find on GLOBAL memory (bridge/accum; path halving, benign races)
__device__ __forceinline__ int ufind(int* par, int i) {
    while (true) {
        int p = par[i];
        if (p == i) return i;
        int gp = par[p];
        if (gp == p) return p;
        par[i] = gp;
        i = gp;
    }
}

__device__ __forceinline__ void uunion(int* par, int a, int b) {
    while (true) {
        a = ufind(par, a);
        b = ufind(par, b);
        if (a == b) return;
        if (a > b) { int t = a; a = b; b = t; }
        int old = atomicCAS(&par[b], b, a);
        if (old == b) return;
        b = old;
    }
}

// ---- union-find on LDS (same code; compiler infers shared addrspace)
__device__ __forceinline__ int lfind(int* par, int i) {
    while (true) {
        int p = par[i];
        if (p == i) return i;
        int gp = par[p];
        if (gp == p) return p;
        par[i] = gp;
        i = gp;
    }
}

__device__ __forceinline__ void luni(int* par, int a, int b) {
    while (true) {
        a = lfind(par, a);
        b = lfind(par, b);
        if (a == b) return;
        if (a > b) { int t = a; a = b; b = t; }
        int old = atomicCAS(&par[b], b, a);
        if (old == b) return;
        b = old;
    }
}

// 1. fused: mask + tile-local CC in LDS + flattened parent write + root gather
//    grid: BB*NTILE blocks of 256
__global__ __launch_bounds__(256) void cc_tile_k(const float* __restrict__ x,
                                                 int* __restrict__ parent,
                                                 int* __restrict__ count,
                                                 int* __restrict__ list) {
    __shared__ int lp[TS * TS];                 // 16 KB
    int blk = blockIdx.x;
    int b = blk / NTILE;
    int t = blk - b * NTILE;
    int th0 = (t / TPS) * TS;
    int tw0 = (t % TPS) * TS;
    int* par = parent + b * HWSZ;

    // load + local init (local idx l: lh=l>>6, lw=l&63; monotone with global idx)
    for (int l = threadIdx.x; l < TS * TS; l += 256) {
        int h = th0 + (l >> 6), w = tw0 + (l & 63);
        int gi = (b * HH + h) * WW + w;
        float tv = x[2 * gi], lv = x[2 * gi + 1];
        lp[l] = (tv > 0.4f || lv > 0.4f) ? l : -1;
    }
    __syncthreads();
    // local unions (mask sign of lp never changes -> race-safe neighbor test)
    for (int l = threadIdx.x; l < TS * TS; l += 256) {
        if (lp[l] < 0) continue;
        if ((l & 63) != 63 && lp[l + 1] >= 0) luni(lp, l, l + 1);
        if (l < TS * TS - TS && lp[l + TS] >= 0) luni(lp, l, l + TS);
    }
    __syncthreads();
    // flatten, write global parent, gather tile-roots
    for (int l = threadIdx.x; l < TS * TS; l += 256) {
        int h = th0 + (l >> 6), w = tw0 + (l & 63);
        int p = h * WW + w;
        if (lp[l] < 0) { par[p] = -1; continue; }
        int r = lfind(lp, l);
        int rp = (th0 + (r >> 6)) * WW + (tw0 + (r & 63));
        par[p] = rp;
        if (r == l) {                            // tile-root: append (pre-bridge)
            int pos = atomicAdd(&count[b], 1);
            if (pos < CAP) list[b * CAP + pos] = p;
        }
    }
}

// 2. cross-tile boundary unions only (BB * 2 dirs * 5 lines * 384 = 15360 threads)
__global__ void bridge_k(int* __restrict__ parent) {
    int i = blockIdx.x * 256 + threadIdx.x;
    if (i >= BB * 2 * (TPS - 1) * WW) return;
    int pos = i % WW; int r = i / WW;
    int line = r % (TPS - 1); r /= (TPS - 1);
    int dir = r & 1; int b = r >> 1;
    int* par = parent + b * HWSZ;
    if (dir == 0) {                              // vertical boundary col 63+64*line
        int p = pos * WW + (TS - 1 + TS * line);
        if (par[p] >= 0 && par[p + 1] >= 0) uunion(par, p, p + 1);
    } else {                                     // horizontal boundary row 63+64*line
        int p = (TS - 1 + TS * line) * WW + pos;
        if (par[p] >= 0 && par[p + WW] >= 0) uunion(par, p, p + WW);
    }
}

// 3. per batch: O(n) selection of the KK smallest still-valid roots, sorted
__global__ __launch_bounds__(256) void select_k(const int* __restrict__ list,
                                                const int* __restrict__ count,
                                                const int* __restrict__ parent,
                                                int* __restrict__ ids) {
    int b = blockIdx.x;
    __shared__ int hist[NB];
    __shared__ int cand[512];
    __shared__ int Bsh, cnt;
    const int* par = parent + b * HWSZ;
    int n = count[b]; if (n > CAP) n = CAP;
    for (int i = threadIdx.x; i < NB; i += 256) hist[i] = 0;
    if (threadIdx.x < KK) ids[b * KK + threadIdx.x] = 0x7FFFFFFF;
    if (threadIdx.x == 0) cnt = 0;
    __syncthreads();
    // histogram of surviving roots (bridge may have demoted some)
    for (int i = threadIdx.x; i < n; i += 256) {
        int v = list[b * CAP + i];
        if (par[v] == v) atomicAdd(&hist[v >> 8], 1);
    }
    __syncthreads();
    if (threadIdx.x == 0) {
        int target = n < KK ? n : KK;
        int c = 0, Bv = NB - 1;
        for (int j = 0; j < NB; ++j) { c += hist[j]; if (c >= target) { Bv = j; break; } }
        Bsh = Bv;
    }
    __syncthreads();
    int B = Bsh;
    for (int i = threadIdx.x; i < n; i += 256) {
        int v = list[b * CAP + i];
        if ((v >> 8) <= B && par[v] == v) {
            int pos = atomicAdd(&cnt, 1);
            if (pos < 512) cand[pos] = v;
        }
    }
    __syncthreads();
    int m = cnt < 512 ? cnt : 512;               // m <= 63 + 256 by construction
    for (int i = threadIdx.x; i < m; i += 256) {
        int v = cand[i];
        int r = 0;
        for (int j = 0; j < m; ++j) r += (cand[j] < v);
        if (r < KK) ids[b * KK + r] = v;
    }
}

// 4. per-pixel: find root, binary-search slot, atomicMin dilated col/row mins
__global__ __launch_bounds__(256) void accum_k(int* __restrict__ parent,
                                               const int* __restrict__ ids,
                                               int* __restrict__ dcol,
                                               int* __restrict__ drow) {
    __shared__ int sids[KK];
    int g = blockIdx.x * 256 + threadIdx.x;
    int b = g / HWSZ, p = g - b * HWSZ;          // block spans one batch
    if (threadIdx.x < KK) sids[threadIdx.x] = ids[b * KK + threadIdx.x];
    __syncthreads();
    if (parent[g] < 0) return;
    int r = ufind(parent + b * HWSZ, p);
    int lo = 0, hi = KK - 1, k = -1;
    while (lo <= hi) {
        int mid = (lo + hi) >> 1;
        int v = sids[mid];
        if (v == r) { k = mid; break; }
        if (v < r) lo = mid + 1; else hi = mid - 1;
    }
    if (k < 0) return;
    int h = p / WW, w = p - h * WW;
    atomicMin(&dcol[(b * KK + k) * WW + w], (h >= 2) ? (h - 2) : h);
    atomicMin(&drow[(b * KK + k) * HH + h], (w >= 2) ? (w - 2) : w);
}

// 5. one block per (b,k): argmax!=0 semantics, reduce, emit bbox
__global__ __launch_bounds__(384) void bbox_k(const int* __restrict__ dcol,
                                              const int* __restrict__ drow,
                                              int* __restrict__ out) {
    int bk = blockIdx.x;
    int t = threadIdx.x;                         // 0..383 == WW == HH
    const int* dc = dcol + bk * WW;
    const int* dr = drow + bk * HH;

    int hm = dc[t];
    if (t >= 2) hm = min(hm, dc[t - 2]);
    if (t + 2 < WW) hm = min(hm, dc[t + 2]);
    bool mc = (hm < INFV) && (hm >= 1);
    int cmin = mc ? t : 0x7FFFFFFF;
    int cmax = mc ? t : -1;

    int wm = dr[t];
    if (t >= 2) wm = min(wm, dr[t - 2]);
    if (t + 2 < HH) wm = min(wm, dr[t + 2]);
    bool mr = (wm < INFV) && (wm >= 1);
    int rmin = mr ? t : 0x7FFFFFFF;
    int rmax = mr ? t : -1;

    for (int o = 1; o < 64; o <<= 1) {
        cmin = min(cmin, __shfl_xor(cmin, o));
        cmax = max(cmax, __shfl_xor(cmax, o));
        rmin = min(rmin, __shfl_xor(rmin, o));
        rmax = max(rmax, __shfl_xor(rmax, o));
    }
    __shared__ int s[4][6];
    int wv = t >> 6;
    if ((t & 63) == 0) { s[0][wv] = cmin; s[1][wv] = cmax; s[2][wv] = rmin; s[3][wv] = rmax; }
    __syncthreads();
    if (t == 0) {
        int CMin = s[0][0], CMax = s[1][0], RMin = s[2][0], RMax = s[3][0];
        for (int i = 1; i < 6; ++i) {
            CMin = min(CMin, s[0][i]); CMax = max(CMax, s[1][i]);
            RMin = min(RMin, s[2][i]); RMax = max(RMax, s[3][i]);
        }
        int x2, y2, wext, hext;
        if (RMax >= 0) { x2 = RMin; wext = RMax - RMin; } else { x2 = 0; wext = 1; }
        if (CMax >= 0) { y2 = CMin; hext = CMax - CMin; } else { y2 = 0; hext = 1; }
        out[bk * 4 + 0] = x2;
        out[bk * 4 + 1] = y2;
        out[bk * 4 + 2] = wext;
        out[bk * 4 + 3] = hext;
    }
}

extern "C" void kernel_launch(void* const* d_in, const int* in_sizes, int n_in,
                              void* d_out, int out_size, void* d_ws, size_t ws_size,
                              hipStream_t stream) {
    const float* x = (const float*)d_in[0];
    int* out = (int*)d_out;

    int* parent = (int*)d_ws;                    // BB*HWSZ
    int* count  = parent + BB * HWSZ;            // BB
    int* ids    = count + BB;                    // BB*KK
    int* list   = ids + BB * KK;                 // BB*CAP
    int* dcol   = list + BB * CAP;               // BB*KK*WW
    int* drow   = dcol + BB * KK * WW;           // BB*KK*HH (contiguous with dcol)

    hipMemsetAsync(count, 0, BB * sizeof(int), stream);
    hipMemsetAsync(dcol, 0x7F, (size_t)BB * KK * (WW + HH) * sizeof(int), stream);

    cc_tile_k<<<BB * NTILE, 256, 0, stream>>>(x, parent, count, list);
    bridge_k<<<(BB * 2 * (TPS - 1) * WW + 255) / 256, 256, 0, stream>>>(parent);
    select_k<<<BB, 256, 0, stream>>>(list, count, parent, ids);
    accum_k<<<BB * HWSZ / 256, 256, 0, stream>>>(parent, ids, dcol, drow);
    bbox_k<<<BB * KK, 384, 0, stream>>>(dcol, drow, out);
}

// Round 5
// 119.439 us; speedup vs baseline: 3.4653x; 1.5303x over previous
//
#include <hip/hip_runtime.h>

#define BB 4
#define HH 384
#define WW 384
#define HWSZ (HH * WW)
#define KK 64
#define CAP 8192
#define TS 64
#define TPS (WW / TS)            // 6 tiles per side
#define NTILE (TPS * TPS)        // 36 per batch
#define NB 576                   // histogram buckets: 147456 >> 8
#define NS 8                     // root-cache slots per accum block
#define AROWS 32                 // rows per accum block (sub-tile)
#define INFI 0x7FFFFFFF
#define INFV 0x7F7F7F7F

// ---- union-find on GLOBAL memory (bridge only; path halving)
__device__ __forceinline__ int ufind(int* par, int i) {
    while (true) {
        int p = par[i];
        if (p == i) return i;
        int gp = par[p];
        if (gp == p) return p;
        par[i] = gp;
        i = gp;
    }
}

__device__ __forceinline__ void uunion(int* par, int a, int b) {
    while (true) {
        a = ufind(par, a);
        b = ufind(par, b);
        if (a == b) return;
        if (a > b) { int t = a; a = b; b = t; }
        int old = atomicCAS(&par[b], b, a);
        if (old == b) return;
        b = old;
    }
}

// ---- union-find on LDS
__device__ __forceinline__ int lfind(int* par, int i) {
    while (true) {
        int p = par[i];
        if (p == i) return i;
        int gp = par[p];
        if (gp == p) return p;
        par[i] = gp;
        i = gp;
    }
}

__device__ __forceinline__ void luni(int* par, int a, int b) {
    while (true) {
        a = lfind(par, a);
        b = lfind(par, b);
        if (a == b) return;
        if (a > b) { int t = a; a = b; b = t; }
        int old = atomicCAS(&par[b], b, a);
        if (old == b) return;
        b = old;
    }
}

// binary search sorted ids (LDS) -> slot or -1
__device__ __forceinline__ int lookup_k(const int* sids, int r) {
    int lo = 0, hi = KK - 1;
    while (lo <= hi) {
        int mid = (lo + hi) >> 1;
        int v = sids[mid];
        if (v == r) return mid;
        if (v < r) lo = mid + 1; else hi = mid - 1;
    }
    return -1;
}

// 1. fused: mask + tile-local CC via run-leaders + flatten + root gather
__global__ __launch_bounds__(256) void cc_tile_k(const float* __restrict__ x,
                                                 int* __restrict__ parent,
                                                 int* __restrict__ count,
                                                 int* __restrict__ list) {
    __shared__ int lp[TS * TS];                 // 16 KB
    int blk = blockIdx.x;
    int b = blk / NTILE;
    int t = blk - b * NTILE;
    int th0 = (t / TPS) * TS;
    int tw0 = (t % TPS) * TS;
    int* par = parent + b * HWSZ;
    int ln = threadIdx.x & 63, wv = threadIdx.x >> 6;

    // pass 1: per-row horizontal run-leaders via ballot (no atomics)
    for (int r = wv; r < TS; r += 4) {
        int h = th0 + r, w = tw0 + ln;
        int gi = (b * HH + h) * WW + w;
        float2 tv = *(const float2*)&x[2 * gi];
        bool m = (tv.x > 0.4f) || (tv.y > 0.4f);
        unsigned long long mb = __ballot(m);
        unsigned long long below = (~mb) & ((1ull << ln) - 1ull);
        int s = below ? (64 - __clzll(below)) : 0;
        lp[r * 64 + ln] = m ? (r * 64 + s) : -1;
    }
    __syncthreads();
    // pass 2: vertical unions, one per overlap-run (dedup via ballot)
    for (int r = wv; r < TS; r += 4) {
        if (r == 0) continue;                    // wave-uniform
        int l = r * 64 + ln;
        bool ov = (lp[l] >= 0) && (lp[l - 64] >= 0);
        unsigned long long ob = __ballot(ov);
        if (ov && (ln == 0 || !((ob >> (ln - 1)) & 1ull)))
            luni(lp, l, l - 64);
    }
    __syncthreads();
    // pass 3: flatten, write global parent, gather tile-roots
    for (int l = threadIdx.x; l < TS * TS; l += 256) {
        int h = th0 + (l >> 6), w = tw0 + (l & 63);
        int p = h * WW + w;
        if (lp[l] < 0) { par[p] = -1; continue; }
        int r = lfind(lp, l);
        par[p] = (th0 + (r >> 6)) * WW + (tw0 + (r & 63));
        if (r == l) {
            int pos = atomicAdd(&count[b], 1);
            if (pos < CAP) list[b * CAP + pos] = p;
        }
    }
}

// 2. cross-tile boundary unions
__global__ void bridge_k(int* __restrict__ parent) {
    int i = blockIdx.x * 256 + threadIdx.x;
    if (i >= BB * 2 * (TPS - 1) * WW) return;
    int pos = i % WW; int r = i / WW;
    int line = r % (TPS - 1); r /= (TPS - 1);
    int dir = r & 1; int b = r >> 1;
    int* par = parent + b * HWSZ;
    if (dir == 0) {
        int p = pos * WW + (TS - 1 + TS * line);
        if (par[p] >= 0 && par[p + 1] >= 0) uunion(par, p, p + 1);
    } else {
        int p = (TS - 1 + TS * line) * WW + pos;
        if (par[p] >= 0 && par[p + WW] >= 0) uunion(par, p, p + WW);
    }
}

// 3. per batch: O(n) selection of the KK smallest surviving roots, sorted
__global__ __launch_bounds__(256) void select_k(const int* __restrict__ list,
                                                const int* __restrict__ count,
                                                const int* __restrict__ parent,
                                                int* __restrict__ ids) {
    int b = blockIdx.x;
    __shared__ int hist[NB];
    __shared__ int cand[512];
    __shared__ int Bsh, cnt;
    const int* par = parent + b * HWSZ;
    int n = count[b]; if (n > CAP) n = CAP;
    for (int i = threadIdx.x; i < NB; i += 256) hist[i] = 0;
    if (threadIdx.x < KK) ids[b * KK + threadIdx.x] = INFI;
    if (threadIdx.x == 0) cnt = 0;
    __syncthreads();
    for (int i = threadIdx.x; i < n; i += 256) {
        int v = list[b * CAP + i];
        if (par[v] == v) atomicAdd(&hist[v >> 8], 1);
    }
    __syncthreads();
    if (threadIdx.x == 0) {
        int target = n < KK ? n : KK;
        int c = 0, Bv = NB - 1;
        for (int j = 0; j < NB; ++j) { c += hist[j]; if (c >= target) { Bv = j; break; } }
        Bsh = Bv;
    }
    __syncthreads();
    int B = Bsh;
    for (int i = threadIdx.x; i < n; i += 256) {
        int v = list[b * CAP + i];
        if ((v >> 8) <= B && par[v] == v) {
            int pos = atomicAdd(&cnt, 1);
            if (pos < 512) cand[pos] = v;
        }
    }
    __syncthreads();
    int m = cnt < 512 ? cnt : 512;
    for (int i = threadIdx.x; i < m; i += 256) {
        int v = cand[i];
        int r = 0;
        for (int j = 0; j < m; ++j) r += (cand[j] < v);
        if (r < KK) ids[b * KK + r] = v;
    }
}

// 4. per sub-tile (32x64): LDS-aggregated dilated col/row mins, then flush
__global__ __launch_bounds__(256) void accum_k(const int* __restrict__ parent,
                                               const int* __restrict__ ids,
                                               int* __restrict__ dcol,
                                               int* __restrict__ drow) {
    __shared__ int sids[KK];
    __shared__ unsigned long long table[NS];     // (root+1)<<32 | (k+2); 0 = empty
    __shared__ int scol[NS][TS];
    __shared__ int srow[NS][AROWS];
    int blk = blockIdx.x;
    int b = blk / (NTILE * 2);
    int rest = blk - b * (NTILE * 2);
    int t = rest >> 1, sub = rest & 1;
    int th0 = (t / TPS) * TS + sub * AROWS;
    int tw0 = (t % TPS) * TS;
    const int* par = parent + b * HWSZ;

    if (threadIdx.x < KK) sids[threadIdx.x] = ids[b * KK + threadIdx.x];
    if (threadIdx.x < NS) table[threadIdx.x] = 0ull;
    for (int i = threadIdx.x; i < NS * TS; i += 256) ((int*)scol)[i] = INFI;
    for (int i = threadIdx.x; i < NS * AROWS; i += 256) ((int*)srow)[i] = INFI;
    __syncthreads();

    for (int c = 0; c < 2; ++c) {
        int base = (threadIdx.x + c * 256) * 4;  // 0..2044, step 4
        int lh = base >> 6, lw = base & 63;
        int h = th0 + lh, w0 = tw0 + lw;
        int p0 = h * WW + w0;
        int4 pr = *(const int4*)&par[p0];
        int fh = (h >= 2) ? h - 2 : h;
        #pragma unroll
        for (int e = 0; e < 4; ++e) {
            int pv = (e == 0) ? pr.x : (e == 1) ? pr.y : (e == 2) ? pr.z : pr.w;
            if (pv < 0) continue;
            int r = pv, nx;
            while ((nx = par[r]) != r) r = nx;   // read-only find (short chain)
            int k = -2, slot = -1;               // -2 = not yet looked up
            for (int i2 = 0; i2 < NS; ++i2) {
                unsigned long long ev = table[i2];
                if (ev == 0ull) {
                    if (k == -2) k = lookup_k(sids, r);
                    unsigned long long me =
                        ((unsigned long long)(unsigned)(r + 1) << 32) | (unsigned)(k + 2);
                    unsigned long long old = atomicCAS(&table[i2], 0ull, me);
                    if (old == 0ull) { slot = i2; break; }
                    ev = old;
                }
                if ((unsigned)(ev >> 32) == (unsigned)(r + 1)) {
                    k = (int)(unsigned)(ev & 0xffffffffull) - 2;
                    slot = i2; break;
                }
            }
            int w = w0 + e;
            int fw = (w >= 2) ? w - 2 : w;
            if (slot >= 0) {
                if (k < 0) continue;             // root not among first KK
                atomicMin(&scol[slot][lw + e], fh);
                atomicMin(&srow[slot][lh], fw);
            } else {                             // table overflow: direct global
                if (k == -2) k = lookup_k(sids, r);
                if (k < 0) continue;
                atomicMin(&dcol[(b * KK + k) * WW + w], fh);
                atomicMin(&drow[(b * KK + k) * HH + h], fw);
            }
        }
    }
    __syncthreads();
    // flush finite entries
    for (int i = threadIdx.x; i < NS * TS; i += 256) {
        int s = i / TS, pos = i - s * TS;
        unsigned long long ev = table[s];
        if (ev == 0ull) continue;
        int k = (int)(unsigned)(ev & 0xffffffffull) - 2;
        if (k < 0) continue;
        int v = scol[s][pos];
        if (v < INFI) atomicMin(&dcol[(b * KK + k) * WW + tw0 + pos], v);
        if (pos < AROWS) {
            int v2 = srow[s][pos];
            if (v2 < INFI) atomicMin(&drow[(b * KK + k) * HH + th0 + pos], v2);
        }
    }
}

// 5. one block per (b,k): argmax!=0 semantics, reduce, emit bbox
__global__ __launch_bounds__(384) void bbox_k(const int* __restrict__ dcol,
                                              const int* __restrict__ drow,
                                              int* __restrict__ out) {
    int bk = blockIdx.x;
    int t = threadIdx.x;                         // 0..383 == WW == HH
    const int* dc = dcol + bk * WW;
    const int* dr = drow + bk * HH;

    int hm = dc[t];
    if (t >= 2) hm = min(hm, dc[t - 2]);
    if (t + 2 < WW) hm = min(hm, dc[t + 2]);
    bool mc = (hm < INFV) && (hm >= 1);
    int cmin = mc ? t : INFI;
    int cmax = mc ? t : -1;

    int wm = dr[t];
    if (t >= 2) wm = min(wm, dr[t - 2]);
    if (t + 2 < HH) wm = min(wm, dr[t + 2]);
    bool mr = (wm < INFV) && (wm >= 1);
    int rmin = mr ? t : INFI;
    int rmax = mr ? t : -1;

    for (int o = 1; o < 64; o <<= 1) {
        cmin = min(cmin, __shfl_xor(cmin, o));
        cmax = max(cmax, __shfl_xor(cmax, o));
        rmin = min(rmin, __shfl_xor(rmin, o));
        rmax = max(rmax, __shfl_xor(rmax, o));
    }
    __shared__ int s[4][6];
    int wv = t >> 6;
    if ((t & 63) == 0) { s[0][wv] = cmin; s[1][wv] = cmax; s[2][wv] = rmin; s[3][wv] = rmax; }
    __syncthreads();
    if (t == 0) {
        int CMin = s[0][0], CMax = s[1][0], RMin = s[2][0], RMax = s[3][0];
        for (int i = 1; i < 6; ++i) {
            CMin = min(CMin, s[0][i]); CMax = max(CMax, s[1][i]);
            RMin = min(RMin, s[2][i]); RMax = max(RMax, s[3][i]);
        }
        int x2, y2, wext, hext;
        if (RMax >= 0) { x2 = RMin; wext = RMax - RMin; } else { x2 = 0; wext = 1; }
        if (CMax >= 0) { y2 = CMin; hext = CMax - CMin; } else { y2 = 0; hext = 1; }
        out[bk * 4 + 0] = x2;
        out[bk * 4 + 1] = y2;
        out[bk * 4 + 2] = wext;
        out[bk * 4 + 3] = hext;
    }
}

extern "C" void kernel_launch(void* const* d_in, const int* in_sizes, int n_in,
                              void* d_out, int out_size, void* d_ws, size_t ws_size,
                              hipStream_t stream) {
    const float* x = (const float*)d_in[0];
    int* out = (int*)d_out;

    int* parent = (int*)d_ws;                    // BB*HWSZ
    int* count  = parent + BB * HWSZ;            // BB
    int* ids    = count + BB;                    // BB*KK
    int* list   = ids + BB * KK;                 // BB*CAP
    int* dcol   = list + BB * CAP;               // BB*KK*WW
    int* drow   = dcol + BB * KK * WW;           // BB*KK*HH (contiguous with dcol)

    hipMemsetAsync(count, 0, BB * sizeof(int), stream);
    hipMemsetAsync(dcol, 0x7F, (size_t)BB * KK * (WW + HH) * sizeof(int), stream);

    cc_tile_k<<<BB * NTILE, 256, 0, stream>>>(x, parent, count, list);
    bridge_k<<<(BB * 2 * (TPS - 1) * WW + 255) / 256, 256, 0, stream>>>(parent);
    select_k<<<BB, 256, 0, stream>>>(list, count, parent, ids);
    accum_k<<<BB * NTILE * 2, 256, 0, stream>>>(parent, ids, dcol, drow);
    bbox_k<<<BB * KK, 384, 0, stream>>>(dcol, drow, out);
}